// Round 1
// baseline (259.733 us; speedup 1.0000x reference)
//
#include <hip/hip_runtime.h>

// FWHT along axis 1 of (64, 1024, 512) fp32, unnormalized (a+b, a-b) stages h=1..512.
// One HBM pass: H_1024 = (H_64 (x) I_16) o (I_64 (x) H_16); stages commute.
// Block = 256 threads, tile = (1 batch, 1024 rows, 16 cols). One __syncthreads.

constexpr int NB = 64;    // batch
constexpr int NR = 1024;  // transform length (axis 1)
constexpr int ND = 512;   // inner dim
constexpr int DC = 16;    // columns per block
constexpr int TPB = 256;

__global__ __launch_bounds__(TPB, 2)
void fwht_kernel(const float* __restrict__ x, float* __restrict__ y) {
    // 1024 x 16 words, bank-swizzled: word(r,c) = (r ^ (g&1))*16 + (c ^ ((g>>1)&15)), g = r>>4.
    // Both access phases verified 2-way (free); naive layout is 16-32-way conflicted.
    __shared__ float lds[NR * DC];  // 65536 B exactly

    const int tid = threadIdx.x;
    // b fastest in blockIdx: line-sharing partner blocks (dg, dg+1) are 64 apart -> same XCD (mod-8 dispatch).
    const int b     = blockIdx.x & 63;
    const int dg    = blockIdx.x >> 6;
    const int dbase = dg * DC;

    // ---- Phase A: coalesced global -> regs (pass-1 layout) ----
    const int g = tid >> 2;  // row-group [0,64)
    const int w = tid & 3;   // col-quad  [0,4)
    const float* src = x + ((size_t)b * NR + (size_t)g * 16) * ND + dbase + w * 4;

    float4 v[16];
#pragma unroll
    for (int j = 0; j < 16; ++j)
        v[j] = *reinterpret_cast<const float4*>(src + (size_t)j * ND);

    // ---- Pass 1: H_16 across j (stages h = 1,2,4,8) ----
#pragma unroll
    for (int hb = 1; hb < 16; hb <<= 1) {
#pragma unroll
        for (int j = 0; j < 16; ++j) {
            if ((j & hb) == 0) {
                const int k = j | hb;
                float4 a = v[j], bb = v[k];
                v[j] = make_float4(a.x + bb.x, a.y + bb.y, a.z + bb.z, a.w + bb.w);
                v[k] = make_float4(a.x - bb.x, a.y - bb.y, a.z - bb.z, a.w - bb.w);
            }
        }
    }

    // ---- Phase C: regs -> LDS, swizzled b32 writes (2 lanes/bank) ----
    {
        const int p0  = g & 1;
        const int S   = (g >> 1) & 15;
        const int Shi = S & 12, Slo = S & 3;
        float* lp = lds + g * 256 + ((w * 4) ^ Shi);
#pragma unroll
        for (int j = 0; j < 16; ++j) {
            float* row = lp + ((j ^ p0) * 16);
            row[0 ^ Slo] = v[j].x;
            row[1 ^ Slo] = v[j].y;
            row[2 ^ Slo] = v[j].z;
            row[3 ^ Slo] = v[j].w;
        }
    }
    __syncthreads();

    // ---- Phase D: LDS -> regs (pass-2 layout: one column, rows j2+16i) ----
    const int j2 = tid >> 4;  // [0,16)
    const int c  = tid & 15;  // [0,16)
    float u[64];
#pragma unroll
    for (int i = 0; i < 64; ++i) {
        const int addr = i * 256 + ((j2 ^ (i & 1)) * 16) + (c ^ ((i >> 1) & 15));
        u[i] = lds[addr];
    }

    // ---- Pass 2: H_64 across i (stages h = 16,32,...,512) ----
#pragma unroll
    for (int hb = 1; hb < 64; hb <<= 1) {
#pragma unroll
        for (int i = 0; i < 64; ++i) {
            if ((i & hb) == 0) {
                const int k = i | hb;
                float a = u[i], bb = u[k];
                u[i] = a + bb;
                u[k] = a - bb;
            }
        }
    }

    // ---- Store: regs -> global (4 x 64 B segments per instr, full lines block-wide) ----
    float* dst = y + ((size_t)b * NR + j2) * ND + dbase + c;
#pragma unroll
    for (int i = 0; i < 64; ++i)
        dst[(size_t)(i * 16) * ND] = u[i];
}

extern "C" void kernel_launch(void* const* d_in, const int* in_sizes, int n_in,
                              void* d_out, int out_size, void* d_ws, size_t ws_size,
                              hipStream_t stream) {
    const float* x = (const float*)d_in[0];
    float* y = (float*)d_out;
    dim3 grid(NB * (ND / DC));  // 2048 blocks
    fwht_kernel<<<grid, TPB, 0, stream>>>(x, y);
}

// Round 2
// 259.068 us; speedup vs baseline: 1.0026x; 1.0026x over previous
//
#include <hip/hip_runtime.h>

// FWHT along axis 1 of (64, 1024, 512) fp32, unnormalized (a+b, a-b), h=1..512.
// One HBM pass: H_1024 = (H_64 (x) I_16) o (I_64 (x) H_16); stages commute.
// Round 2: persistent blocks (grid 512 = 2/CU), 4 tiles/block, cross-tile
// register prefetch. Raw s_barrier (no vmcnt drain) so loads/stores stay in
// flight across barriers. Stores via second LDS round-trip -> 16x dwordx4,
// keeping outstanding vmem at 16 loads + 16 stores so the compiler can wait
// vmcnt(16) for prefetched data instead of vmcnt(0).

constexpr int NB = 64;    // batch
constexpr int NR = 1024;  // transform length (axis 1)
constexpr int ND = 512;   // inner dim
constexpr int DC = 16;    // columns per tile
constexpr int TPB = 256;
constexpr int GRID = 512;             // 2 blocks/CU, all resident
constexpr int TPT = (NB * (ND / DC)) / GRID;  // 4 tiles per block

// Workgroup barrier WITHOUT the compiler's vmcnt(0) drain: LDS ops must be
// complete (lgkmcnt 0) but global loads/stores may remain in flight.
#define BAR() asm volatile("s_waitcnt lgkmcnt(0)\n\ts_barrier" ::: "memory")

__global__ __launch_bounds__(TPB, 2)
void fwht_kernel(const float* __restrict__ x, float* __restrict__ y) {
    __shared__ float lds[NR * DC];  // 65536 B

    const int tid = threadIdx.x;
    const int pid = blockIdx.x;     // 0..511
    const int b   = pid & 63;       // batch (invariant across tiles)
    const int dg0 = pid >> 6;       // 0..7; tile t uses dg = dg0 + 8t

    const int g  = tid >> 2;  // phase A/F row-group [0,64)
    const int w  = tid & 3;   // phase A/F col-quad  [0,4)
    const int j2 = tid >> 4;  // phase D/E row-in-group [0,16)
    const int c  = tid & 15;  // phase D/E column       [0,16)

    // base offset for phase A loads / phase F stores (row 16g, col quad w)
    const size_t rowA = ((size_t)b * NR + (size_t)g * 16) * ND + (size_t)(w * 4);

    // ---- preload tile 0 ----
    float4 v[16];
    {
        const float* src = x + rowA + dg0 * DC;
#pragma unroll
        for (int j = 0; j < 16; ++j)
            v[j] = *reinterpret_cast<const float4*>(src + (size_t)j * ND);
    }

#pragma unroll
    for (int t = 0; t < TPT; ++t) {
        const int dbase = (dg0 + 8 * t) * DC;

        // ---- prefetch tile t+1 (in flight across this whole iteration) ----
        float4 vn[16];
        if (t < TPT - 1) {
            const float* srcn = x + rowA + (dbase + 8 * DC);
#pragma unroll
            for (int j = 0; j < 16; ++j)
                vn[j] = *reinterpret_cast<const float4*>(srcn + (size_t)j * ND);
        }

        // ---- Pass 1: H_16 across j (stages h=1,2,4,8); waits vmcnt(16) ----
#pragma unroll
        for (int hb = 1; hb < 16; hb <<= 1) {
#pragma unroll
            for (int j = 0; j < 16; ++j) {
                if ((j & hb) == 0) {
                    const int k = j | hb;
                    float4 a = v[j], bb = v[k];
                    v[j] = make_float4(a.x + bb.x, a.y + bb.y, a.z + bb.z, a.w + bb.w);
                    v[k] = make_float4(a.x - bb.x, a.y - bb.y, a.z - bb.z, a.w - bb.w);
                }
            }
        }

        // ---- Phase C: regs -> LDS, layout-1 swizzle (2 lanes/bank, free) ----
        {
            const int p0  = g & 1;
            const int S   = (g >> 1) & 15;
            const int Shi = S & 12, Slo = S & 3;
            float* lp = lds + g * 256 + ((w * 4) ^ Shi);
#pragma unroll
            for (int j = 0; j < 16; ++j) {
                float* row = lp + ((j ^ p0) * 16);
                row[0 ^ Slo] = v[j].x;
                row[1 ^ Slo] = v[j].y;
                row[2 ^ Slo] = v[j].z;
                row[3 ^ Slo] = v[j].w;
            }
        }
        BAR();

        // ---- Phase D: LDS -> regs, layout-1 (one column, rows j2+16i) ----
        float u[64];
#pragma unroll
        for (int i = 0; i < 64; ++i) {
            const int addr = i * 256 + ((j2 ^ (i & 1)) * 16) + (c ^ ((i >> 1) & 15));
            u[i] = lds[addr];
        }

        // ---- Pass 2: H_64 across i (stages h=16..512) ----
#pragma unroll
        for (int hb = 1; hb < 64; hb <<= 1) {
#pragma unroll
            for (int i = 0; i < 64; ++i) {
                if ((i & hb) == 0) {
                    const int k = i | hb;
                    float a = u[i], bb = u[k];
                    u[i] = a + bb;
                    u[k] = a - bb;
                }
            }
        }
        BAR();  // all phase-D reads done before layout-2 overwrites

        // ---- Phase E: u -> LDS, layout-2: word = r*16 + (c ^ 4*(i&3)) ----
        // banks: 2 lanes/bank (free)
#pragma unroll
        for (int i = 0; i < 64; ++i)
            lds[256 * i + 16 * j2 + (c ^ ((i & 3) << 2))] = u[i];
        BAR();

        // ---- Phase F: LDS -> float4 regs -> 16x global_store_dwordx4 ----
        {
            float* dst = y + rowA + dbase;
            const int cg = (w ^ (g & 3)) << 2;
#pragma unroll
            for (int j = 0; j < 16; ++j) {
                float4 wv = *reinterpret_cast<const float4*>(&lds[(16 * g + j) * 16 + cg]);
                *reinterpret_cast<float4*>(dst + (size_t)j * ND) = wv;
            }
        }
        BAR();  // all phase-F reads done before next iter's phase-C writes

        // ---- rotate prefetch buffer ----
        if (t < TPT - 1) {
#pragma unroll
            for (int j = 0; j < 16; ++j) v[j] = vn[j];
        }
    }
}

extern "C" void kernel_launch(void* const* d_in, const int* in_sizes, int n_in,
                              void* d_out, int out_size, void* d_ws, size_t ws_size,
                              hipStream_t stream) {
    const float* x = (const float*)d_in[0];
    float* y = (float*)d_out;
    fwht_kernel<<<dim3(GRID), dim3(TPB), 0, stream>>>(x, y);
}